// Round 13
// baseline (61.367 us; speedup 1.0000x reference)
//
#include <hip/hip_runtime.h>
#include <math.h>

#define HIDDEN 256
#define BATCH 8192
#define NEGS 16
#define NSCORES (BATCH + BATCH * NEGS)  // 139264
#define PI2 6.28318530717958647692f
#define FR_STRIDE 136                   // float2 per rel row (129 used)

typedef unsigned int uint32;
typedef _Float16 h2v __attribute__((ext_vector_type(2)));

__device__ __forceinline__ float2 cmul(float2 a, float2 b) {
    return make_float2(fmaf(a.x, b.x, -a.y * b.y), fmaf(a.x, b.y, a.y * b.x));
}
__device__ __forceinline__ float2 cmulc(float2 a, float cx, float cy) {
    return make_float2(fmaf(a.x, cx, -a.y * cy), fmaf(a.x, cy, a.y * cx));
}
__device__ __forceinline__ float2 mulnegi(float2 a) { return make_float2(a.y, -a.x); }

__device__ __forceinline__ uint32 pk(float a, float b) {
    auto p = __builtin_amdgcn_cvt_pkrtz(a, b);
    uint32 u; __builtin_memcpy(&u, &p, 4);
    return u;
}
__device__ __forceinline__ float2 unpk(uint32 u) {
    h2v h; __builtin_memcpy(&h, &u, 4);
    return make_float2((float)h.x, (float)h.y);
}

// DPP cross-lane (VALU): quad_perm xor1=0xB1, xor2=0x4E, row_mirror=0x140
template<int C>
__device__ __forceinline__ float fdpp(float v) {
    return __uint_as_float((unsigned)__builtin_amdgcn_mov_dpp(
        (int)__float_as_uint(v), C, 0xf, 0xf, true));
}
// ds_swizzle: xor4=0x101F, xor8=0x201F
template<int IMM>
__device__ __forceinline__ float fswz(float v) {
    return __uint_as_float((unsigned)__builtin_amdgcn_ds_swizzle(
        (int)__float_as_uint(v), IMM));
}

// radix-4 DIF butterfly: u_k = DFT4 at freq k (W4 = -i)
__device__ __forceinline__ void bfly4(float2 a, float2 b, float2 c, float2 d,
                                      float2& u0, float2& u1, float2& u2, float2& u3) {
    float2 apc = make_float2(a.x + c.x, a.y + c.y);
    float2 amc = make_float2(a.x - c.x, a.y - c.y);
    float2 bpd = make_float2(b.x + d.x, b.y + d.y);
    float2 bmd = make_float2(b.x - d.x, b.y - d.y);
    u0 = make_float2(apc.x + bpd.x, apc.y + bpd.y);
    u2 = make_float2(apc.x - bpd.x, apc.y - bpd.y);
    u1 = make_float2(amc.x + bmd.y, amc.y - bmd.x);   // (a-c) - i(b-d)
    u3 = make_float2(amc.x - bmd.y, amc.y + bmd.x);   // (a-c) + i(b-d)
}

// In-register 16-point complex DFT (DIF radix-4), natural-order in/out.
__device__ __forceinline__ void fft16(float2 z[16]) {
    const float R  = 0.70710678118654752440f;
    const float C1 = 0.92387953251128675613f;
    const float S1 = 0.38268343236508977173f;
    #pragma unroll
    for (int p = 0; p < 4; ++p) {
        float2 u0, u1, u2, u3;
        bfly4(z[p], z[p+4], z[p+8], z[p+12], u0, u1, u2, u3);
        z[p] = u0; z[p+4] = u1; z[p+8] = u2; z[p+12] = u3;
    }
    z[5]  = cmulc(z[5],  C1, -S1);
    z[6]  = cmulc(z[6],  R,  -R );
    z[7]  = cmulc(z[7],  S1, -C1);
    z[9]  = cmulc(z[9],  R,  -R );
    z[10] = mulnegi(z[10]);
    z[11] = cmulc(z[11], -R, -R );
    z[13] = cmulc(z[13], S1, -C1);
    z[14] = cmulc(z[14], -R, -R );
    z[15] = cmulc(z[15], -C1, S1);
    float2 o[16];
    #pragma unroll
    for (int k = 0; k < 4; ++k) {
        float2 v0, v1, v2, v3;
        bfly4(z[4*k], z[4*k+1], z[4*k+2], z[4*k+3], v0, v1, v2, v3);
        o[k] = v0; o[k+4] = v1; o[k+8] = v2; o[k+12] = v3;
    }
    #pragma unroll
    for (int i = 0; i < 16; ++i) z[i] = o[i];
}

// z[f1] *= W256^{L*f1} -- register-light
__device__ __forceinline__ void twiddle256(float2 z[16], int L) {
    float s1, c1, s4, c4;
    __sincosf(-PI2 * (1.0f / 256.0f) * (float)L, &s1, &c1);
    __sincosf(-PI2 * (1.0f / 64.0f) * (float)L, &s4, &c4);
    const float2 w1 = make_float2(c1, s1);
    const float2 w4 = make_float2(c4, s4);
    const float2 w2 = cmul(w1, w1);
    const float2 w3 = cmul(w2, w1);
    z[1] = cmul(z[1], w1); z[2] = cmul(z[2], w2); z[3] = cmul(z[3], w3);
    float2 m = w4;
    #pragma unroll
    for (int a = 1; a < 4; ++a) {
        z[4*a]   = cmul(z[4*a], m);
        z[4*a+1] = cmul(cmul(z[4*a+1], m), w1);
        z[4*a+2] = cmul(cmul(z[4*a+2], m), w2);
        z[4*a+3] = cmul(cmul(z[4*a+3], m), w3);
        if (a < 3) m = cmul(m, w4);
    }
}

// lane digit map: sig(15-L) = 16 - sig(L) (mod 16 for L=0/15 pair)
__device__ __forceinline__ int sigmap(int L) {
    return (L == 0) ? 0 : (L == 15 ? 8 : (L < 8 ? L : L + 1));
}

// ---------------- rel pre-FFT (four-step, 16 rows per block) ----------------
// Emits the HALF table (r real => Fr[256-f] = conj Fr[f]); see R11 comment.
#define RRS 18
#define RGS (16 * RRS + 2)

__global__ __launch_bounds__(256) void rel_fft_kernel(
    const float* __restrict__ rel, float2* __restrict__ FrH)
{
    __shared__ __align__(16) float2 Tr[16 * RGS];
    const int tid = threadIdx.x;
    const int gb = tid >> 4;
    const int L = tid & 15;
    const int ri = blockIdx.x * 16 + gb;
    if (ri >= 1000) return;

    const float* __restrict__ rrow = rel + (long)ri * HIDDEN;
    float2 z[16];
    float rn2 = 0.f;
    #pragma unroll
    for (int n1 = 0; n1 < 16; ++n1) {
        const float v = rrow[16 * n1 + L];
        z[n1] = make_float2(v, 0.f);
        rn2 = fmaf(v, v, rn2);
    }
    rn2 += fdpp<0xB1>(rn2);
    rn2 += fdpp<0x4E>(rn2);
    rn2 += fswz<0x101F>(rn2);
    rn2 += fswz<0x201F>(rn2);
    const float s = rsqrtf(fmaxf(rn2, 1e-12f)) * (1.0f / 256.0f);

    fft16(z);
    twiddle256(z, L);

    float2* __restrict__ Tg = Tr + gb * RGS;
    {
        float4* __restrict__ wp4 = (float4*)(Tg + L * RRS);
        #pragma unroll
        for (int j = 0; j < 8; ++j)
            wp4[j] = make_float4(z[2*j].x, z[2*j].y, z[2*j+1].x, z[2*j+1].y);
    }
    const int sig = sigmap(L);
    __builtin_amdgcn_wave_barrier();
    #pragma unroll
    for (int n2 = 0; n2 < 16; ++n2) z[n2] = Tg[n2 * RRS + sig];

    fft16(z);   // lane holds Fr[sig + 16*f2] in reg f2

    float2* __restrict__ ob = FrH + (long)ri * FR_STRIDE + sig;
    #pragma unroll
    for (int f2 = 0; f2 < 8; ++f2) {
        float cx = s * z[f2].x;
        float cy = 0.5f * s * z[f2].y;
        if (sig == 0 && f2 == 0) { cx *= 0.5f; cy = 0.f; }
        ob[16 * f2] = make_float2(cx, cy);
    }
    if (L == 0)
        FrH[(long)ri * FR_STRIDE + 128] = make_float2(0.5f * s * z[8].x, 0.f);
}

// ---------------- score kernel (folds neg-mean per batch row) ----------------
// Blocks 0..511: 16 positive scores -> p[s]. Blocks 512..8703: the 16 negatives
// of batch row (blk-512) -> nmean[row] (deterministic serial 16-sum by tid 0).
#define RSU 20
#define GSU (16 * RSU + 4)

__global__ __launch_bounds__(256, 7) void score_kernel(
    const int* __restrict__ pos_h, const int* __restrict__ pos_t, const int* __restrict__ pos_r,
    const int* __restrict__ neg_h, const int* __restrict__ neg_t, const int* __restrict__ neg_r,
    const float* __restrict__ ent, const float2* __restrict__ FrH,
    float* __restrict__ p_out, float* __restrict__ nmean_out)
{
    __shared__ __align__(16) uint32 Tu[16 * GSU];   // 20.7 KB
    __shared__ float nbuf[16];
    const int tid = threadIdx.x;
    const int gb = tid >> 4;
    const int L = tid & 15;
    const int s = blockIdx.x * 16 + gb;

    const bool isp = s < BATCH;
    const int jj = isp ? s : s - BATCH;
    const int hi = (isp ? pos_h : neg_h)[jj];
    const int ti = (isp ? pos_t : neg_t)[jj];
    const int ri = (isp ? pos_r : neg_r)[jj];

    const float* __restrict__ hrow = ent + (long)hi * HIDDEN;
    const float* __restrict__ trow = ent + (long)ti * HIDDEN;

    float2 z[16];
    #pragma unroll
    for (int n1 = 0; n1 < 16; ++n1)
        z[n1] = make_float2(hrow[16 * n1 + L], trow[16 * n1 + L]);

    fft16(z);
    twiddle256(z, L);

    uint32* __restrict__ Tg = Tu + gb * GSU;
    {
        uint4* __restrict__ wp4 = (uint4*)(Tg + L * RSU);
        #pragma unroll
        for (int j = 0; j < 4; ++j)
            wp4[j] = make_uint4(pk(z[4*j].x,   z[4*j].y),
                                pk(z[4*j+1].x, z[4*j+1].y),
                                pk(z[4*j+2].x, z[4*j+2].y),
                                pk(z[4*j+3].x, z[4*j+3].y));
    }

    const int sig = sigmap(L);

    __builtin_amdgcn_wave_barrier();
    #pragma unroll
    for (int n2 = 0; n2 < 16; ++n2) z[n2] = unpk(Tg[n2 * RSU + sig]);

    fft16(z);   // Z[f2] = X[sig + 16 f2]

    const float2* __restrict__ fb = FrH + (long)ri * FR_STRIDE + sig;
    float2 fr[8];
    #pragma unroll
    for (int f2 = 0; f2 < 8; ++f2) fr[f2] = fb[16 * f2];
    const float2 c128 = FrH[(long)ri * FR_STRIDE + 128];

    const bool isL0 = (L == 0), isL15 = (L == 15);
    float S = 0.f;
    #pragma unroll
    for (int f2 = 0; f2 < 8; ++f2) {
        float2 src = z[15 - f2];
        float2 Bm = make_float2(fdpp<0x140>(src.x), fdpp<0x140>(src.y));
        float2 own0 = z[(16 - f2) & 15];
        float2 B;
        B.x = isL0 ? own0.x : (isL15 ? src.x : Bm.x);
        B.y = isL0 ? own0.y : (isL15 ? src.y : Bm.y);
        const float2 A = z[f2];
        const float imAB = A.x * B.y + A.y * B.x;
        const float dmag = (B.x * B.x + B.y * B.y) - (A.x * A.x + A.y * A.y);
        S = fmaf(fr[f2].x, imAB, fmaf(fr[f2].y, dmag, S));
    }
    if (isL0) S = fmaf(c128.x, 2.f * z[8].x * z[8].y, S);

    // reduce across the 16-lane group
    S += fdpp<0xB1>(S);
    S += fdpp<0x4E>(S);
    S += fswz<0x101F>(S);
    S += fswz<0x201F>(S);

    if (isp) {
        if (L == 0) p_out[s] = -1.0f / (1.0f + __expf(-S));
    } else {
        if (L == 0) nbuf[gb] = -1.0f / (1.0f + __expf(-S));
        __syncthreads();
        if (tid == 0) {
            float n = 0.f;
            #pragma unroll
            for (int i = 0; i < 16; ++i) n += nbuf[i];
            nmean_out[blockIdx.x - BATCH / 16] = n * (1.0f / NEGS);
        }
    }
}

// Single-block loss: reads p[8192] + nmean[8192] (64 KB), overwrites out[0].
__global__ __launch_bounds__(1024) void loss_kernel(
    const float* __restrict__ p, const float* __restrict__ nmean,
    float* __restrict__ out)
{
    __shared__ float red[16];
    float v = 0.f;
    #pragma unroll
    for (int k = 0; k < BATCH / 1024; ++k) {
        const int b = threadIdx.x + 1024 * k;
        v += fmaxf(p[b] - nmean[b] + 1.0f, 0.0f);
    }
    #pragma unroll
    for (int m = 32; m >= 1; m >>= 1) v += __shfl_xor(v, m);
    const int wave = threadIdx.x >> 6, lane = threadIdx.x & 63;
    if (lane == 0) red[wave] = v;
    __syncthreads();
    if (threadIdx.x < 16) {
        float w = red[threadIdx.x];
        #pragma unroll
        for (int m = 8; m >= 1; m >>= 1) w += __shfl_xor(w, m, 16);
        if (threadIdx.x == 0) out[0] = w;
    }
}

extern "C" void kernel_launch(void* const* d_in, const int* in_sizes, int n_in,
                              void* d_out, int out_size, void* d_ws, size_t ws_size,
                              hipStream_t stream) {
    (void)in_sizes; (void)n_in; (void)out_size; (void)ws_size;
    const int* pos_h = (const int*)d_in[0];
    const int* pos_t = (const int*)d_in[1];
    const int* pos_r = (const int*)d_in[2];
    const int* neg_h = (const int*)d_in[3];
    const int* neg_t = (const int*)d_in[4];
    const int* neg_r = (const int*)d_in[5];
    const float* ent = (const float*)d_in[6];
    const float* rel = (const float*)d_in[7];

    float2* FrH = (float2*)d_ws;                                    // 1,088,000 B
    float* p = (float*)((char*)d_ws + 1000 * FR_STRIDE * sizeof(float2));
    float* nmean = p + BATCH;
    float* out = (float*)d_out;

    rel_fft_kernel<<<dim3(63), dim3(256), 0, stream>>>(rel, FrH);
    score_kernel<<<dim3(NSCORES / 16), dim3(256), 0, stream>>>(
        pos_h, pos_t, pos_r, neg_h, neg_t, neg_r, ent, FrH, p, nmean);
    loss_kernel<<<dim3(1), dim3(1024), 0, stream>>>(p, nmean, out);
}